// Round 6
// baseline (512.143 us; speedup 1.0000x reference)
//
#include <hip/hip_runtime.h>
#include <math.h>

#define V 2
#define NN 100000
#define KK 8
#define DD 128
#define TILE_N 128
#define SL 132
#define LOG2PI 1.8378770664093454f
#define LOG_1EM6 -13.815510557964274f

// ws layout (bytes):
//  G: [16][69632]  per-(v,k) padded bf16 image: hi rows 0..127 stride 136 ushorts
//                  (34816 B), then lo (34816 B). Copied verbatim to LDS.
//  b: [16][128] float  @ 1114112
//  c: [16] float       @ 1122304
#define IMG_B 69632
#define IMG_HALF 17408      /* ushorts per half (128 rows * 136) */
#define BV_B  1114112
#define C_B   1122304

// out layout (floats): energies [N][V] | weights [N][V] | total_energies | total_penalty
#define OUT_W_OFF (NN*V)
#define OUT_TE (2*NN*V)
#define OUT_TP (2*NN*V + 1)

typedef __attribute__((ext_vector_type(8))) short bf16x8;
typedef __attribute__((ext_vector_type(4))) float f32x4;

__device__ __forceinline__ unsigned short f2bf_rtn(float f) {
    unsigned u = __builtin_bit_cast(unsigned, f);
    unsigned r = u + 0x7FFFu + ((u >> 16) & 1u);
    return (unsigned short)(r >> 16);
}
__device__ __forceinline__ float bf2f(unsigned short h) {
    unsigned u = ((unsigned)h) << 16;
    return __builtin_bit_cast(float, u);
}

__global__ void zero_kernel(float* out) {
    int t = threadIdx.x;
    if (t < 2) out[OUT_TE + t] = 0.0f;
}

// One block of 256 threads per (v,k).
// 16 panel phases; wave0 factors each 8-col panel wave-synchronously; rank-8
// register-tile trailing update; restricted float4 trsm. (proven in round 5)
__global__ __launch_bounds__(256) void prep_kernel(const float* __restrict__ phi,
                                                   const float* __restrict__ mu,
                                                   const float* __restrict__ sigma,
                                                   void* __restrict__ wsv,
                                                   float* __restrict__ out) {
    __shared__ float Lf[DD * SL];          // L row-major, stride 132 (upper zeroed)
    __shared__ float Wcm[DD * SL];         // W col-major: Wcm[j*SL+i] = W[i][j]
    __shared__ float P[8][SL];             // current panel, col-major
    __shared__ float dvec[DD];             // raw pivots d_c = L_cc^2
    __shared__ float mulds[DD];
    __shared__ float red[256];
    __shared__ float Bv[8];

    const int tid = threadIdx.x;           // 0..255
    const int vk  = blockIdx.x;            // 0..15
    const int v   = vk >> 3;
    const int k   = vk & 7;
    const int R   = tid >> 4;              // tile rows 8R..8R+7
    const int C   = tid & 15;              // tile cols 8C..8C+7

    if (tid < DD) mulds[tid] = mu[vk * DD + tid];

    // Load 8x8 register tile of sigma (+1e-6 I).
    float A[8][8];
    const float* sig = sigma + (size_t)vk * DD * DD;
    float pen = 0.0f;
    #pragma unroll
    for (int a = 0; a < 8; ++a) {
        const float4* p4 = (const float4*)(sig + (size_t)(8 * R + a) * DD + 8 * C);
        float4 x = p4[0], y = p4[1];
        A[a][0] = x.x; A[a][1] = x.y; A[a][2] = x.z; A[a][3] = x.w;
        A[a][4] = y.x; A[a][5] = y.y; A[a][6] = y.z; A[a][7] = y.w;
        if (R == C) A[a][a] += 1e-6f;
    }
    if (R == C) {
        #pragma unroll
        for (int a = 0; a < 8; ++a) pen += 1.0f / (A[a][a] + 1e-12f);
    }

    // zero Lf (so float4 tails hit exact zeros) and Wcm
    for (int i = tid; i < DD * SL; i += 256) { Lf[i] = 0.0f; Wcm[i] = 0.0f; }

    // penalty reduce
    red[tid] = pen;
    __syncthreads();
    for (int s = 128; s > 0; s >>= 1) {
        if (tid < s) red[tid] += red[tid + s];
        __syncthreads();
    }
    if (tid == 0) atomicAdd(&out[OUT_TP], red[0]);
    __syncthreads();

    // ---- 16 panel phases ----
    for (int p = 0; p < 16; ++p) {
        // publish raw panel (cols 8p..8p+7, rows >= 8p)
        if (C == p && R >= p) {
            #pragma unroll
            for (int b = 0; b < 8; ++b) {
                *(float4*)&P[b][8 * R]     = make_float4(A[0][b], A[1][b], A[2][b], A[3][b]);
                *(float4*)&P[b][8 * R + 4] = make_float4(A[4][b], A[5][b], A[6][b], A[7][b]);
            }
        }
        __syncthreads();

        // wave0: factor the panel wave-synchronously
        if (tid < 64) {
            const int lane = tid;
            const int r1 = 8 * p + lane;
            const int r2 = r1 + 64;
            const bool ok2 = (r2 < DD);
            float pr1[8], pr2[8], rs[8];
            #pragma unroll
            for (int j = 0; j < 8; ++j) {
                pr1[j] = (r1 < DD) ? P[j][r1] : 0.0f;
                pr2[j] = ok2 ? P[j][r2] : 0.0f;
            }
            #pragma unroll
            for (int j = 0; j < 8; ++j) {
                if (lane >= j && lane < 8) Bv[lane] = pr1[j];
                __builtin_amdgcn_wave_barrier();
                float bv[8];
                #pragma unroll
                for (int m = 0; m < 8; ++m) bv[m] = Bv[m];
                __builtin_amdgcn_wave_barrier();
                float piv = bv[j];
                if (lane == j) dvec[8 * p + j] = piv;
                float inv2 = 1.0f / piv;
                rs[j] = rsqrtf(piv);
                float m1 = pr1[j] * inv2;
                float m2 = pr2[j] * inv2;
                #pragma unroll
                for (int j2 = 0; j2 < 8; ++j2) {
                    if (j2 > j) {
                        if (lane > j) pr1[j2] -= m1 * bv[j2];
                        pr2[j2] -= m2 * bv[j2];
                    }
                }
            }
            // writeback scaled L panel (zeros above diag)
            #pragma unroll
            for (int j = 0; j < 8; ++j) {
                if (r1 < DD) {
                    float v1 = (lane >= j) ? pr1[j] * rs[j] : 0.0f;
                    P[j][r1] = v1;
                    Lf[r1 * SL + 8 * p + j] = v1;
                }
                if (ok2) {
                    float v2 = pr2[j] * rs[j];
                    P[j][r2] = v2;
                    Lf[r2 * SL + 8 * p + j] = v2;
                }
            }
        }
        __syncthreads();

        // rank-8 trailing update
        if (C > p && R >= p) {
            #pragma unroll
            for (int j = 0; j < 8; ++j) {
                float4 a0 = *(const float4*)&P[j][8 * R];
                float4 a1 = *(const float4*)&P[j][8 * R + 4];
                float4 b0 = *(const float4*)&P[j][8 * C];
                float4 b1 = *(const float4*)&P[j][8 * C + 4];
                float ra[8] = {a0.x, a0.y, a0.z, a0.w, a1.x, a1.y, a1.z, a1.w};
                float rb[8] = {b0.x, b0.y, b0.z, b0.w, b1.x, b1.y, b1.z, b1.w};
                #pragma unroll
                for (int a = 0; a < 8; ++a)
                    #pragma unroll
                    for (int b = 0; b < 8; ++b)
                        A[a][b] -= ra[a] * rb[b];
            }
        }
        __syncthreads();
    }

    // trsm: W = L^{-1}. Thread pair per column; i from j+1; aligned float4 reads.
    {
        const int j = tid >> 1;
        const int par = tid & 1;
        if (par == 0) Wcm[j * SL + j] = 1.0f / Lf[j * SL + j];
        __builtin_amdgcn_wave_barrier();
        const int pj0 = (j & ~3) + 4 * par;
        for (int i = j + 1; i < DD; ++i) {
            float s = 0.0f;
            for (int p4 = pj0; p4 < i; p4 += 8) {
                float4 lf = *(const float4*)&Lf[i * SL + p4];
                float4 wc = *(const float4*)&Wcm[j * SL + p4];
                s += lf.x * wc.x + lf.y * wc.y + lf.z * wc.z + lf.w * wc.w;
            }
            s += __shfl_xor(s, 1, 64);
            if (par == 0)
                Wcm[j * SL + i] = -s / Lf[i * SL + i];
        }
    }
    __syncthreads();

    // b_i = sum_j W[i][j] mu[j]
    if (tid < DD) {
        float b = 0.0f;
        for (int j2 = 0; j2 < DD; ++j2)
            b += Wcm[j2 * SL + tid] * mulds[j2];
        ((float*)((char*)wsv + BV_B))[vk * DD + tid] = b;
    }

    // pack W -> bf16 hi/lo padded global image (row stride 136 ushorts; hi then lo).
    {
        unsigned* Gp = (unsigned*)((char*)wsv + (size_t)vk * IMG_B);
        const int r = tid >> 1;
        const int half = (tid & 1) * 64;
        for (int d0 = half; d0 < half + 64; d0 += 2) {
            float f0 = Wcm[d0 * SL + r];
            float f1 = Wcm[(d0 + 1) * SL + r];
            unsigned short h0 = f2bf_rtn(f0);
            unsigned short h1 = f2bf_rtn(f1);
            unsigned short l0 = f2bf_rtn(f0 - bf2f(h0));
            unsigned short l1 = f2bf_rtn(f1 - bf2f(h1));
            int wi = (r * 136 + d0) >> 1;
            Gp[wi] = (unsigned)h0 | ((unsigned)h1 << 16);
            Gp[(IMG_HALF >> 1) + wi] = (unsigned)l0 | ((unsigned)l1 << 16);
        }
    }

    // logdet = sum log d_c (clipped at log 1e-6)
    red[tid] = (tid < DD) ? logf(dvec[tid]) : 0.0f;
    __syncthreads();
    for (int s = 128; s > 0; s >>= 1) {
        if (tid < s) red[tid] += red[tid + s];
        __syncthreads();
    }
    if (tid == 0) {
        float logdet_c = fmaxf(red[0], LOG_1EM6);
        const float* ph = phi + v * KK;
        float m = ph[0];
        for (int i = 1; i < KK; ++i) m = fmaxf(m, ph[i]);
        float s = 0.0f;
        for (int i = 0; i < KK; ++i) s += expf(ph[i] - m);
        float logpi = ph[k] - m - logf(s);
        ((float*)((char*)wsv + C_B))[vk] = logpi - 0.5f * logdet_c - 0.5f * (float)DD * LOG2PI;
    }
}

// Main: double-buffered W pipeline. Per round r=(v,k): prefetch W(r+1) into the
// other LDS buffer, compute round r, then one __syncthreads (its vmcnt(0) drain
// lands AFTER compute, when the DMA has had the whole compute phase to finish).
__global__ __launch_bounds__(256) void energy_kernel(const float* __restrict__ z,
                                                     const void* __restrict__ wsv,
                                                     float* __restrict__ out) {
    __shared__ char wbuf[2 * IMG_B];            // 139264 B
    __shared__ float maha_s[V][TILE_N][KK + 1]; // 9216 B
    __shared__ float bl_all[16][DD];            // 8192 B
    __shared__ float clds[16];
    __shared__ float red[256];

    const int tid  = threadIdx.x;
    const int lane = tid & 63;
    const int wave = tid >> 6;
    const int quad = lane >> 4;
    const int l16  = lane & 15;
    const int n0   = blockIdx.x * TILE_N;

    const float* b_g = (const float*)((const char*)wsv + BV_B);
    const float* c_g = (const float*)((const char*)wsv + C_B);

    // preload constants
    for (int i = tid; i < 16 * DD; i += 256) ((float*)bl_all)[i] = b_g[i];
    if (tid < 16) clds[tid] = c_g[tid];

    // staging helper (inlined twice below): wave-chunked 1KB DMA, 17 chunks
    const int lane_off = wave * 1024 + lane * 16;

    // prologue: stage round 0 into buffer 0
    {
        const char* src = (const char*)wsv + 0 * IMG_B;
        char* dst = wbuf;
        #pragma unroll
        for (int t = 0; t < 17; ++t)
            __builtin_amdgcn_global_load_lds(
                (const __attribute__((address_space(1))) void*)(src + t * 4096 + lane_off),
                (__attribute__((address_space(3))) void*)(dst + t * 4096 + wave * 1024),
                16, 0, 0);
    }

    // z fragments for v=0
    bf16x8 zhi[2][4], zlo[2][4];
    #pragma unroll
    for (int mt = 0; mt < 2; ++mt) {
        int n = n0 + wave * 32 + mt * 16 + l16;
        bool ok = (n < NN);
        const float* zp = z + ((size_t)0 * NN + n) * DD + quad * 8;
        #pragma unroll
        for (int ds = 0; ds < 4; ++ds) {
            float f[8];
            if (ok) {
                float4 a  = *(const float4*)(zp + ds * 32);
                float4 bq = *(const float4*)(zp + ds * 32 + 4);
                f[0] = a.x;  f[1] = a.y;  f[2] = a.z;  f[3] = a.w;
                f[4] = bq.x; f[5] = bq.y; f[6] = bq.z; f[7] = bq.w;
            } else {
                #pragma unroll
                for (int e = 0; e < 8; ++e) f[e] = 0.0f;
            }
            bf16x8 hi8, lo8;
            #pragma unroll
            for (int e = 0; e < 8; ++e) {
                unsigned short hu = f2bf_rtn(f[e]);
                unsigned short lu = f2bf_rtn(f[e] - bf2f(hu));
                hi8[e] = (short)hu;
                lo8[e] = (short)lu;
            }
            zhi[mt][ds] = hi8;
            zlo[mt][ds] = lo8;
        }
    }
    __syncthreads();   // buf0 + bl_all ready

    for (int r = 0; r < 16; ++r) {
        const int vv  = r >> 3;
        const int k   = r & 7;
        const int cur = r & 1;

        // v-boundary: reload z fragments (before issuing next DMA, so the
        // conversion's vmcnt wait doesn't have to drain the prefetch)
        if (r == 8) {
            #pragma unroll
            for (int mt = 0; mt < 2; ++mt) {
                int n = n0 + wave * 32 + mt * 16 + l16;
                bool ok = (n < NN);
                const float* zp = z + ((size_t)1 * NN + n) * DD + quad * 8;
                #pragma unroll
                for (int ds = 0; ds < 4; ++ds) {
                    float f[8];
                    if (ok) {
                        float4 a  = *(const float4*)(zp + ds * 32);
                        float4 bq = *(const float4*)(zp + ds * 32 + 4);
                        f[0] = a.x;  f[1] = a.y;  f[2] = a.z;  f[3] = a.w;
                        f[4] = bq.x; f[5] = bq.y; f[6] = bq.z; f[7] = bq.w;
                    } else {
                        #pragma unroll
                        for (int e = 0; e < 8; ++e) f[e] = 0.0f;
                    }
                    bf16x8 hi8, lo8;
                    #pragma unroll
                    for (int e = 0; e < 8; ++e) {
                        unsigned short hu = f2bf_rtn(f[e]);
                        unsigned short lu = f2bf_rtn(f[e] - bf2f(hu));
                        hi8[e] = (short)hu;
                        lo8[e] = (short)lu;
                    }
                    zhi[mt][ds] = hi8;
                    zlo[mt][ds] = lo8;
                }
            }
        }

        // prefetch round r+1 into the other buffer
        if (r < 15) {
            const char* src = (const char*)wsv + (size_t)(r + 1) * IMG_B;
            char* dst = wbuf + (1 - cur) * IMG_B;
            #pragma unroll
            for (int t = 0; t < 17; ++t)
                __builtin_amdgcn_global_load_lds(
                    (const __attribute__((address_space(1))) void*)(src + t * 4096 + lane_off),
                    (__attribute__((address_space(3))) void*)(dst + t * 4096 + wave * 1024),
                    16, 0, 0);
        }

        // compute round r from buffer cur
        const unsigned short* wb = (const unsigned short*)(wbuf + cur * IMG_B);

        f32x4 acc[2][8];
        #pragma unroll
        for (int mt = 0; mt < 2; ++mt)
            #pragma unroll
            for (int nt = 0; nt < 8; ++nt)
                acc[mt][nt] = (f32x4)(0.0f);

        #pragma unroll
        for (int ds = 0; ds < 4; ++ds) {
            const int g = ds * 4 + quad;
            #pragma unroll
            for (int nt = 0; nt < 8; ++nt) {
                if (nt < 2 * ds) continue;   // W tile exactly zero (lower-triangular)
                int row = nt * 16 + l16;
                int off = row * 136 + g * 8;
                bf16x8 bh  = *(const bf16x8*)&wb[off];
                bf16x8 blo = *(const bf16x8*)&wb[IMG_HALF + off];
                #pragma unroll
                for (int mt = 0; mt < 2; ++mt) {
                    acc[mt][nt] = __builtin_amdgcn_mfma_f32_16x16x32_bf16(zhi[mt][ds], bh,  acc[mt][nt], 0, 0, 0);
                    acc[mt][nt] = __builtin_amdgcn_mfma_f32_16x16x32_bf16(zhi[mt][ds], blo, acc[mt][nt], 0, 0, 0);
                    acc[mt][nt] = __builtin_amdgcn_mfma_f32_16x16x32_bf16(zlo[mt][ds], bh,  acc[mt][nt], 0, 0, 0);
                }
            }
        }

        // epilogue: maha[n][k] = sum_rows (y - b)^2 via quad-group shfl reduce
        #pragma unroll
        for (int mt = 0; mt < 2; ++mt) {
            float p[4] = {0.f, 0.f, 0.f, 0.f};
            #pragma unroll
            for (int nt = 0; nt < 8; ++nt) {
                float bc = bl_all[r][nt * 16 + l16];
                f32x4 a = acc[mt][nt];
                float y0 = a[0] - bc, y1 = a[1] - bc, y2 = a[2] - bc, y3 = a[3] - bc;
                p[0] += y0 * y0; p[1] += y1 * y1; p[2] += y2 * y2; p[3] += y3 * y3;
            }
            #pragma unroll
            for (int reg = 0; reg < 4; ++reg) {
                float s = p[reg];
                s += __shfl_xor(s, 1, 64);
                s += __shfl_xor(s, 2, 64);
                s += __shfl_xor(s, 4, 64);
                s += __shfl_xor(s, 8, 64);
                if (l16 == 0)
                    maha_s[vv][wave * 32 + mt * 16 + quad * 4 + reg][k] = s;
            }
        }

        __syncthreads();   // drains prefetch DMA (post-compute) + wave sync
    }

    // LSE + outputs
    float esum = 0.0f;
    if (tid < TILE_N && (n0 + tid) < NN) {
        float ev[V];
        #pragma unroll
        for (int vv = 0; vv < V; ++vv) {
            float lp[KK];
            float m = -1e30f;
            #pragma unroll
            for (int k = 0; k < KK; ++k) {
                lp[k] = -0.5f * maha_s[vv][tid][k] + clds[vv * KK + k];
                m = fmaxf(m, lp[k]);
            }
            float s = 0.0f;
            #pragma unroll
            for (int k = 0; k < KK; ++k) s += expf(lp[k] - m);
            ev[vv] = -(m + logf(s));
        }
        int n = n0 + tid;
        float e0 = ev[0], e1 = ev[1];
        float m = fmaxf(-e0, -e1);
        float x0 = expf(-e0 - m);
        float x1 = expf(-e1 - m);
        float inv = 1.0f / (x0 + x1);
        out[(size_t)n * V + 0] = e0;
        out[(size_t)n * V + 1] = e1;
        out[OUT_W_OFF + (size_t)n * V + 0] = x0 * inv;
        out[OUT_W_OFF + (size_t)n * V + 1] = x1 * inv;
        esum = e0 + e1;
    }

    red[tid] = esum;
    __syncthreads();
    for (int s = 128; s > 0; s >>= 1) {
        if (tid < s) red[tid] += red[tid + s];
        __syncthreads();
    }
    if (tid == 0) atomicAdd(&out[OUT_TE], red[0]);
}

extern "C" void kernel_launch(void* const* d_in, const int* in_sizes, int n_in,
                              void* d_out, int out_size, void* d_ws, size_t ws_size,
                              hipStream_t stream) {
    const float* z     = (const float*)d_in[0];
    const float* phi   = (const float*)d_in[1];
    const float* mu    = (const float*)d_in[2];
    const float* sigma = (const float*)d_in[3];
    float* out = (float*)d_out;

    hipLaunchKernelGGL(zero_kernel, dim3(1), dim3(64), 0, stream, out);
    hipLaunchKernelGGL(prep_kernel, dim3(V * KK), dim3(256), 0, stream, phi, mu, sigma, d_ws, out);
    int nblocks = (NN + TILE_N - 1) / TILE_N;
    hipLaunchKernelGGL(energy_kernel, dim3(nblocks), dim3(256), 0, stream, z, d_ws, out);
}

// Round 7
// 400.492 us; speedup vs baseline: 1.2788x; 1.2788x over previous
//
#include <hip/hip_runtime.h>
#include <math.h>

#define V 2
#define NN 100000
#define KK 8
#define DD 128
#define TILE_N 128
#define SL 132
#define NT 782            /* ceil(100000/128) */
#define CH 8              /* tiles per maha block */
#define NCHUNK 98         /* ceil(782/8) */
#define NPAD 100096       /* NT*128 */
#define LOG2PI 1.8378770664093454f
#define LOG_1EM6 -13.815510557964274f

// ws layout (bytes):
//  IMG:  [16][69632]  padded bf16 image: hi rows stride 136 ushorts, then lo
//  LF:   [16][69632]  L fp32 row-major stride 132 (67584 B used)
//  B:    [16][128] float
//  C:    [16] float
//  MAHA: [16][NPAD] float
#define IMG_B 69632
#define IMG_HALF 17408      /* ushorts per half */
#define LF_B   1114112
#define BV_B   2228224
#define C_B    2236416
#define MAHA_B 2236480

// out layout (floats): energies [N][V] | weights [N][V] | total_energies | total_penalty
#define OUT_W_OFF (NN*V)
#define OUT_TE (2*NN*V)
#define OUT_TP (2*NN*V + 1)

typedef __attribute__((ext_vector_type(8))) short bf16x8;
typedef __attribute__((ext_vector_type(4))) float f32x4;

__device__ __forceinline__ unsigned short f2bf_rtn(float f) {
    unsigned u = __builtin_bit_cast(unsigned, f);
    unsigned r = u + 0x7FFFu + ((u >> 16) & 1u);
    return (unsigned short)(r >> 16);
}
__device__ __forceinline__ float bf2f(unsigned short h) {
    unsigned u = ((unsigned)h) << 16;
    return __builtin_bit_cast(float, u);
}

__global__ void zero_kernel(float* out) {
    int t = threadIdx.x;
    if (t < 2) out[OUT_TE + t] = 0.0f;
}

// One block of 256 threads per (v,k): panel Cholesky (proven round 5),
// forward solve L b = mu, write L + b + c + penalty/logdet.
__global__ __launch_bounds__(256) void prep_chol(const float* __restrict__ phi,
                                                 const float* __restrict__ mu,
                                                 const float* __restrict__ sigma,
                                                 void* __restrict__ wsv,
                                                 float* __restrict__ out) {
    __shared__ float Lf[DD * SL];          // L row-major, stride 132 (upper zeroed)
    __shared__ float P[8][SL];             // current panel, col-major
    __shared__ float dvec[DD];             // raw pivots d_c = L_cc^2
    __shared__ float mulds[DD];
    __shared__ float red[256];
    __shared__ float Bv[8];
    __shared__ float Bb[DD];

    const int tid = threadIdx.x;
    const int vk  = blockIdx.x;
    const int v   = vk >> 3;
    const int k   = vk & 7;
    const int R   = tid >> 4;
    const int C   = tid & 15;

    if (tid < DD) mulds[tid] = mu[vk * DD + tid];

    float A[8][8];
    const float* sig = sigma + (size_t)vk * DD * DD;
    float pen = 0.0f;
    #pragma unroll
    for (int a = 0; a < 8; ++a) {
        const float4* p4 = (const float4*)(sig + (size_t)(8 * R + a) * DD + 8 * C);
        float4 x = p4[0], y = p4[1];
        A[a][0] = x.x; A[a][1] = x.y; A[a][2] = x.z; A[a][3] = x.w;
        A[a][4] = y.x; A[a][5] = y.y; A[a][6] = y.z; A[a][7] = y.w;
        if (R == C) A[a][a] += 1e-6f;
    }
    if (R == C) {
        #pragma unroll
        for (int a = 0; a < 8; ++a) pen += 1.0f / (A[a][a] + 1e-12f);
    }

    for (int i = tid; i < DD * SL; i += 256) Lf[i] = 0.0f;

    red[tid] = pen;
    __syncthreads();
    for (int s = 128; s > 0; s >>= 1) {
        if (tid < s) red[tid] += red[tid + s];
        __syncthreads();
    }
    if (tid == 0) atomicAdd(&out[OUT_TP], red[0]);
    __syncthreads();

    // ---- 16 panel phases ----
    for (int p = 0; p < 16; ++p) {
        if (C == p && R >= p) {
            #pragma unroll
            for (int b = 0; b < 8; ++b) {
                *(float4*)&P[b][8 * R]     = make_float4(A[0][b], A[1][b], A[2][b], A[3][b]);
                *(float4*)&P[b][8 * R + 4] = make_float4(A[4][b], A[5][b], A[6][b], A[7][b]);
            }
        }
        __syncthreads();

        if (tid < 64) {
            const int lane = tid;
            const int r1 = 8 * p + lane;
            const int r2 = r1 + 64;
            const bool ok2 = (r2 < DD);
            float pr1[8], pr2[8], rs[8];
            #pragma unroll
            for (int j = 0; j < 8; ++j) {
                pr1[j] = (r1 < DD) ? P[j][r1] : 0.0f;
                pr2[j] = ok2 ? P[j][r2] : 0.0f;
            }
            #pragma unroll
            for (int j = 0; j < 8; ++j) {
                if (lane >= j && lane < 8) Bv[lane] = pr1[j];
                __builtin_amdgcn_wave_barrier();
                float bv[8];
                #pragma unroll
                for (int m = 0; m < 8; ++m) bv[m] = Bv[m];
                __builtin_amdgcn_wave_barrier();
                float piv = bv[j];
                if (lane == j) dvec[8 * p + j] = piv;
                float inv2 = 1.0f / piv;
                rs[j] = rsqrtf(piv);
                float m1 = pr1[j] * inv2;
                float m2 = pr2[j] * inv2;
                #pragma unroll
                for (int j2 = 0; j2 < 8; ++j2) {
                    if (j2 > j) {
                        if (lane > j) pr1[j2] -= m1 * bv[j2];
                        pr2[j2] -= m2 * bv[j2];
                    }
                }
            }
            #pragma unroll
            for (int j = 0; j < 8; ++j) {
                if (r1 < DD) {
                    float v1 = (lane >= j) ? pr1[j] * rs[j] : 0.0f;
                    P[j][r1] = v1;
                    Lf[r1 * SL + 8 * p + j] = v1;
                }
                if (ok2) {
                    float v2 = pr2[j] * rs[j];
                    P[j][r2] = v2;
                    Lf[r2 * SL + 8 * p + j] = v2;
                }
            }
        }
        __syncthreads();

        if (C > p && R >= p) {
            #pragma unroll
            for (int j = 0; j < 8; ++j) {
                float4 a0 = *(const float4*)&P[j][8 * R];
                float4 a1 = *(const float4*)&P[j][8 * R + 4];
                float4 b0 = *(const float4*)&P[j][8 * C];
                float4 b1 = *(const float4*)&P[j][8 * C + 4];
                float ra[8] = {a0.x, a0.y, a0.z, a0.w, a1.x, a1.y, a1.z, a1.w};
                float rb[8] = {b0.x, b0.y, b0.z, b0.w, b1.x, b1.y, b1.z, b1.w};
                #pragma unroll
                for (int a = 0; a < 8; ++a)
                    #pragma unroll
                    for (int b = 0; b < 8; ++b)
                        A[a][b] -= ra[a] * rb[b];
            }
        }
        __syncthreads();
    }

    // forward solve L b = mu (wave 0, wave-synchronous)
    if (tid < 64) {
        const int lane = tid;
        float acc0 = mulds[lane];
        float acc1 = mulds[lane + 64];
        for (int j = 0; j < DD; ++j) {
            if (j < 64) { if (lane == j)      Bb[j] = acc0 / Lf[j * SL + j]; }
            else        { if (lane == j - 64) Bb[j] = acc1 / Lf[j * SL + j]; }
            __builtin_amdgcn_wave_barrier();
            float bj = Bb[j];
            __builtin_amdgcn_wave_barrier();
            if (lane > j)      acc0 -= Lf[lane * SL + j] * bj;
            if (lane + 64 > j) acc1 -= Lf[(lane + 64) * SL + j] * bj;
        }
    }
    __syncthreads();
    if (tid < DD) ((float*)((char*)wsv + BV_B))[vk * DD + tid] = Bb[tid];

    // write L to global (fp32, stride 132)
    {
        float4* Lg = (float4*)((char*)wsv + LF_B + (size_t)vk * IMG_B);
        const float4* Ls4 = (const float4*)Lf;
        for (int i = tid; i < DD * SL / 4; i += 256) Lg[i] = Ls4[i];
    }

    // logdet = sum log d_c (clipped) + c_k
    red[tid] = (tid < DD) ? logf(dvec[tid]) : 0.0f;
    __syncthreads();
    for (int s = 128; s > 0; s >>= 1) {
        if (tid < s) red[tid] += red[tid + s];
        __syncthreads();
    }
    if (tid == 0) {
        float logdet_c = fmaxf(red[0], LOG_1EM6);
        const float* ph = phi + v * KK;
        float m = ph[0];
        for (int i = 1; i < KK; ++i) m = fmaxf(m, ph[i]);
        float s = 0.0f;
        for (int i = 0; i < KK; ++i) s += expf(ph[i] - m);
        float logpi = ph[k] - m - logf(s);
        ((float*)((char*)wsv + C_B))[vk] = logpi - 0.5f * logdet_c - 0.5f * (float)DD * LOG2PI;
    }
}

// 64 blocks: (vk, column-group). Each block computes 32 columns of W = L^{-1}
// (8 lanes per column) and packs them into the bf16 hi/lo padded image.
__global__ __launch_bounds__(256) void prep_trsm(void* __restrict__ wsv) {
    __shared__ float Ls[DD * SL];
    __shared__ float Wc[32][SL];

    const int tid = threadIdx.x;
    const int vk  = blockIdx.x >> 2;
    const int cg  = blockIdx.x & 3;

    const float4* Lg = (const float4*)((const char*)wsv + LF_B + (size_t)vk * IMG_B);
    float4* Ls4 = (float4*)Ls;
    for (int i = tid; i < DD * SL / 4; i += 256) Ls4[i] = Lg[i];
    __syncthreads();

    const int c   = tid >> 3;          // local column 0..31
    const int par = tid & 7;
    const int j   = 4 * c + cg;        // global column

    for (int e = par; e < SL; e += 8) Wc[c][e] = 0.0f;
    if (par == 0) Wc[c][j] = 1.0f / Ls[j * SL + j];
    __builtin_amdgcn_wave_barrier();

    const int pbase = j & ~3;
    for (int i = j + 1; i < DD; ++i) {
        float s = 0.0f;
        for (int p4 = pbase + 4 * par; p4 < i; p4 += 32) {
            float4 lf = *(const float4*)&Ls[i * SL + p4];
            float4 wc = *(const float4*)&Wc[c][p4];
            s += lf.x * wc.x + lf.y * wc.y + lf.z * wc.z + lf.w * wc.w;
        }
        s += __shfl_xor(s, 1, 64);
        s += __shfl_xor(s, 2, 64);
        s += __shfl_xor(s, 4, 64);
        if (par == 0) Wc[c][i] = -s / Ls[i * SL + i];
        __builtin_amdgcn_wave_barrier();
    }

    // pack column j into padded image
    unsigned short* Gh = (unsigned short*)((char*)wsv + (size_t)vk * IMG_B);
    unsigned short* Gl = Gh + IMG_HALF;
    for (int i2 = par; i2 < DD; i2 += 8) {
        float f = (i2 >= j) ? Wc[c][i2] : 0.0f;
        unsigned short h = f2bf_rtn(f);
        unsigned short l = f2bf_rtn(f - bf2f(h));
        Gh[i2 * 136 + j] = h;
        Gl[i2 * 136 + j] = l;
    }
}

// grid (98, 16): block = (chunk, round). Stage W_r into LDS ONCE, then
// free-run over up to 8 z-tiles: global->VGPR z loads (no LDS alias, no
// barriers, no DMA in the loop), split-bf16 triangular MFMA, write raw
// maha[r][n] to ws.
__global__ __launch_bounds__(256, 2) void maha_kernel(const float* __restrict__ z,
                                                      void* __restrict__ wsv) {
    __shared__ unsigned short wl[IMG_B / 2];
    __shared__ float bl_s[DD];

    const int tid  = threadIdx.x;
    const int lane = tid & 63;
    const int wave = tid >> 6;
    const int quad = lane >> 4;
    const int l16  = lane & 15;
    const int r     = blockIdx.y;       // 0..15
    const int chunk = blockIdx.x;       // 0..97
    const int vv    = r >> 3;

    // stage W_r (17 x 4KB chunks, exact: IMG_B = 17*4096)
    {
        const char* src = (const char*)wsv + (size_t)r * IMG_B;
        char* dst = (char*)wl;
        const int lane_off = wave * 1024 + lane * 16;
        #pragma unroll
        for (int t = 0; t < 17; ++t)
            __builtin_amdgcn_global_load_lds(
                (const __attribute__((address_space(1))) void*)(src + t * 4096 + lane_off),
                (__attribute__((address_space(3))) void*)(dst + t * 4096 + wave * 1024),
                16, 0, 0);
    }
    if (tid < DD) bl_s[tid] = ((const float*)((const char*)wsv + BV_B))[r * DD + tid];
    __syncthreads();   // single drain; nothing in-flight afterwards

    const float* zbase = z + (size_t)vv * NN * DD;
    float* mrow = (float*)((char*)wsv + MAHA_B) + (size_t)r * NPAD;

    for (int ti = 0; ti < CH; ++ti) {
        const int t = chunk * CH + ti;
        if (t >= NT) break;
        const int n0 = t * TILE_N;

        // z fragments -> registers (bf16 hi/lo split)
        bf16x8 zhi[2][4], zlo[2][4];
        #pragma unroll
        for (int mt = 0; mt < 2; ++mt) {
            int n = n0 + wave * 32 + mt * 16 + l16;
            bool ok = (n < NN);
            const float* zp = zbase + (size_t)n * DD + quad * 8;
            #pragma unroll
            for (int ds = 0; ds < 4; ++ds) {
                float f[8];
                if (ok) {
                    float4 a  = *(const float4*)(zp + ds * 32);
                    float4 bq = *(const float4*)(zp + ds * 32 + 4);
                    f[0] = a.x;  f[1] = a.y;  f[2] = a.z;  f[3] = a.w;
                    f[4] = bq.x; f[5] = bq.y; f[6] = bq.z; f[7] = bq.w;
                } else {
                    #pragma unroll
                    for (int e = 0; e < 8; ++e) f[e] = 0.0f;
                }
                bf16x8 hi8, lo8;
                #pragma unroll
                for (int e = 0; e < 8; ++e) {
                    unsigned short hu = f2bf_rtn(f[e]);
                    unsigned short lu = f2bf_rtn(f[e] - bf2f(hu));
                    hi8[e] = (short)hu;
                    lo8[e] = (short)lu;
                }
                zhi[mt][ds] = hi8;
                zlo[mt][ds] = lo8;
            }
        }

        f32x4 acc[2][8];
        #pragma unroll
        for (int mt = 0; mt < 2; ++mt)
            #pragma unroll
            for (int nt = 0; nt < 8; ++nt)
                acc[mt][nt] = (f32x4)(0.0f);

        #pragma unroll
        for (int ds = 0; ds < 4; ++ds) {
            const int g = ds * 4 + quad;
            #pragma unroll
            for (int nt = 0; nt < 8; ++nt) {
                if (nt < 2 * ds) continue;   // W tile exactly zero (lower-triangular)
                int row = nt * 16 + l16;
                int off = row * 136 + g * 8;
                bf16x8 bh  = *(const bf16x8*)&wl[off];
                bf16x8 blo = *(const bf16x8*)&wl[IMG_HALF + off];
                #pragma unroll
                for (int mt = 0; mt < 2; ++mt) {
                    acc[mt][nt] = __builtin_amdgcn_mfma_f32_16x16x32_bf16(zhi[mt][ds], bh,  acc[mt][nt], 0, 0, 0);
                    acc[mt][nt] = __builtin_amdgcn_mfma_f32_16x16x32_bf16(zhi[mt][ds], blo, acc[mt][nt], 0, 0, 0);
                    acc[mt][nt] = __builtin_amdgcn_mfma_f32_16x16x32_bf16(zlo[mt][ds], bh,  acc[mt][nt], 0, 0, 0);
                }
            }
        }

        // epilogue: maha = sum_rows (y-b)^2, quad-group shfl reduce, float4 store
        #pragma unroll
        for (int mt = 0; mt < 2; ++mt) {
            float p[4] = {0.f, 0.f, 0.f, 0.f};
            #pragma unroll
            for (int nt = 0; nt < 8; ++nt) {
                float bc = bl_s[nt * 16 + l16];
                f32x4 a = acc[mt][nt];
                float y0 = a[0] - bc, y1 = a[1] - bc, y2 = a[2] - bc, y3 = a[3] - bc;
                p[0] += y0 * y0; p[1] += y1 * y1; p[2] += y2 * y2; p[3] += y3 * y3;
            }
            float sv[4];
            #pragma unroll
            for (int reg = 0; reg < 4; ++reg) {
                float s = p[reg];
                s += __shfl_xor(s, 1, 64);
                s += __shfl_xor(s, 2, 64);
                s += __shfl_xor(s, 4, 64);
                s += __shfl_xor(s, 8, 64);
                sv[reg] = s;
            }
            if (l16 == 0)
                *(float4*)&mrow[n0 + wave * 32 + mt * 16 + quad * 4] =
                    make_float4(sv[0], sv[1], sv[2], sv[3]);
        }
    }
}

// LSE + weights + totals from maha[16][NPAD].
__global__ __launch_bounds__(256) void finalize_kernel(const void* __restrict__ wsv,
                                                       float* __restrict__ out) {
    __shared__ float red[256];
    __shared__ float clds[16];

    const int tid = threadIdx.x;
    if (tid < 16) clds[tid] = ((const float*)((const char*)wsv + C_B))[tid];
    __syncthreads();

    const float* mahap = (const float*)((const char*)wsv + MAHA_B);
    const int n = blockIdx.x * 256 + tid;
    float esum = 0.0f;

    if (n < NN) {
        float ev[V];
        #pragma unroll
        for (int vv = 0; vv < V; ++vv) {
            float lp[KK];
            float m = -1e30f;
            #pragma unroll
            for (int k = 0; k < KK; ++k) {
                int r = vv * KK + k;
                lp[k] = -0.5f * mahap[(size_t)r * NPAD + n] + clds[r];
                m = fmaxf(m, lp[k]);
            }
            float s = 0.0f;
            #pragma unroll
            for (int k = 0; k < KK; ++k) s += expf(lp[k] - m);
            ev[vv] = -(m + logf(s));
        }
        float e0 = ev[0], e1 = ev[1];
        float m = fmaxf(-e0, -e1);
        float x0 = expf(-e0 - m);
        float x1 = expf(-e1 - m);
        float inv = 1.0f / (x0 + x1);
        out[(size_t)n * V + 0] = e0;
        out[(size_t)n * V + 1] = e1;
        out[OUT_W_OFF + (size_t)n * V + 0] = x0 * inv;
        out[OUT_W_OFF + (size_t)n * V + 1] = x1 * inv;
        esum = e0 + e1;
    }

    red[tid] = esum;
    __syncthreads();
    for (int s = 128; s > 0; s >>= 1) {
        if (tid < s) red[tid] += red[tid + s];
        __syncthreads();
    }
    if (tid == 0) atomicAdd(&out[OUT_TE], red[0]);
}

extern "C" void kernel_launch(void* const* d_in, const int* in_sizes, int n_in,
                              void* d_out, int out_size, void* d_ws, size_t ws_size,
                              hipStream_t stream) {
    const float* z     = (const float*)d_in[0];
    const float* phi   = (const float*)d_in[1];
    const float* mu    = (const float*)d_in[2];
    const float* sigma = (const float*)d_in[3];
    float* out = (float*)d_out;

    hipLaunchKernelGGL(zero_kernel, dim3(1), dim3(64), 0, stream, out);
    hipLaunchKernelGGL(prep_chol, dim3(V * KK), dim3(256), 0, stream, phi, mu, sigma, d_ws, out);
    hipLaunchKernelGGL(prep_trsm, dim3(64), dim3(256), 0, stream, d_ws);
    hipLaunchKernelGGL(maha_kernel, dim3(NCHUNK, 16), dim3(256), 0, stream, z, d_ws);
    hipLaunchKernelGGL(finalize_kernel, dim3((NPAD + 255) / 256), dim3(256), 0, stream, d_ws, out);
}